// Round 1
// 8125.187 us; speedup vs baseline: 1.7363x; 1.7363x over previous
//
#include <hip/hip_runtime.h>
#include <stdint.h>
#include <math.h>

// Problem constants
#define NTOK 4096   // B*T
#define TSEQ 2048
#define CDIM 1024
#define NHEAD 16
#define DHEAD 64
#define NEXP 8
#define HIDN 4096
#define ECAP 1024

// ---------------- threefry2x32 (exact JAX semantics) ----------------
__device__ __forceinline__ void threefry2x32(uint32_t k0, uint32_t k1,
                                             uint32_t x0, uint32_t x1,
                                             uint32_t& o0, uint32_t& o1) {
  uint32_t ks2 = k0 ^ k1 ^ 0x1BD11BDAu;
#define TF_R(r) { x0 += x1; x1 = (x1 << (r)) | (x1 >> (32 - (r))); x1 ^= x0; }
  x0 += k0; x1 += k1;
  TF_R(13) TF_R(15) TF_R(26) TF_R(6)
  x0 += k1; x1 += ks2 + 1u;
  TF_R(17) TF_R(29) TF_R(16) TF_R(24)
  x0 += ks2; x1 += k0 + 2u;
  TF_R(13) TF_R(15) TF_R(26) TF_R(6)
  x0 += k0; x1 += k1 + 3u;
  TF_R(17) TF_R(29) TF_R(16) TF_R(24)
  x0 += k1; x1 += ks2 + 4u;
  TF_R(13) TF_R(15) TF_R(26) TF_R(6)
  x0 += ks2; x1 += k0 + 5u;
#undef TF_R
  o0 = x0; o1 = x1;
}

// XLA's f32 erf_inv (Giles 2012 polynomial, log1p variant)
__device__ __forceinline__ float erfinv_f32(float x) {
  float w = -log1pf(-x * x);
  float p;
  if (w < 5.0f) {
    w = w - 2.5f;
    p = 2.81022636e-08f;
    p = fmaf(p, w, 3.43273939e-07f);
    p = fmaf(p, w, -3.5233877e-06f);
    p = fmaf(p, w, -4.39150654e-06f);
    p = fmaf(p, w, 0.00021858087f);
    p = fmaf(p, w, -0.00125372503f);
    p = fmaf(p, w, -0.00417768164f);
    p = fmaf(p, w, 0.246640727f);
    p = fmaf(p, w, 1.50140941f);
  } else {
    w = sqrtf(w) - 3.0f;
    p = -0.000200214257f;
    p = fmaf(p, w, 0.000100950558f);
    p = fmaf(p, w, 0.00134934322f);
    p = fmaf(p, w, -0.00367342844f);
    p = fmaf(p, w, 0.00573950773f);
    p = fmaf(p, w, -0.0076224613f);
    p = fmaf(p, w, 0.00943887047f);
    p = fmaf(p, w, 1.00167406f);
    p = fmaf(p, w, 2.83297682f);
  }
  return p * x;
}

// ---------------- embedding ----------------
__global__ __launch_bounds__(256) void k_embed(const int* __restrict__ ids,
    const float* __restrict__ tok, const float* __restrict__ pos,
    float* __restrict__ x) {
  int row = blockIdx.x;
  int id = ids[row];
  int t = row & (TSEQ - 1);
  const float* tr = tok + (size_t)id * CDIM;
  const float* pr = pos + (size_t)t * CDIM;
  float* xr = x + (size_t)row * CDIM;
  for (int c = threadIdx.x; c < CDIM; c += 256) xr[c] = tr[c] + pr[c];
}

// ---------------- layernorm (two-pass, matches jnp.var) ----------------
__global__ __launch_bounds__(256) void k_ln(const float* __restrict__ in,
    float* __restrict__ out, const float* __restrict__ g, const float* __restrict__ b) {
  __shared__ float red[256];
  int row = blockIdx.x, tid = threadIdx.x;
  const float* xr = in + (size_t)row * CDIM;
  float s = 0.f;
  for (int c = tid; c < CDIM; c += 256) s += xr[c];
  red[tid] = s; __syncthreads();
  for (int off = 128; off > 0; off >>= 1) {
    if (tid < off) red[tid] += red[tid + off];
    __syncthreads();
  }
  float m = red[0] * (1.0f / CDIM);
  __syncthreads();
  float v = 0.f;
  for (int c = tid; c < CDIM; c += 256) { float d = xr[c] - m; v += d * d; }
  red[tid] = v; __syncthreads();
  for (int off = 128; off > 0; off >>= 1) {
    if (tid < off) red[tid] += red[tid + off];
    __syncthreads();
  }
  float var = red[0] * (1.0f / CDIM);
  float rstd = 1.0f / sqrtf(var + 1e-5f);
  float* orow = out + (size_t)row * CDIM;
  for (int c = tid; c < CDIM; c += 256)
    orow[c] = (xr[c] - m) * rstd * g[c] + b[c];
}

// ---------------- high-throughput tiled fp32 GEMM ----------------
// 128x128 tile per 256-thread block, 8x8 per thread, BK=16, k-major LDS,
// register-prefetch pipeline. Optional per-z (blockIdx.z) batching via
// element strides (expert batching). C[M,N] (flags&2: +=) =
// act( A[gather?][K] @ B[K,N] + bias ); flags&1: relu.
// countPtr[z]: Meff = min(M, count) row limit (device-side).
__global__ __launch_bounds__(256, 2) void k_gemm(
    const float* __restrict__ A, int lda,
    const float* __restrict__ B, int ldb,
    float* __restrict__ Cm, int ldc,
    int M, int N, int K,
    const float* __restrict__ bias,
    const int* __restrict__ gather,
    const int* __restrict__ countPtr,
    int flags,
    size_t zsA, size_t zsB, size_t zsC, int zsBias, int zsGather) {
  __shared__ float As[16][132];   // k-major, padded: conflict-free frag reads
  __shared__ float Bs[16][128];   // k-major, rows match global layout
  const int z = blockIdx.z;
  A += (size_t)z * zsA;
  B += (size_t)z * zsB;
  Cm += (size_t)z * zsC;
  if (bias) bias += (size_t)z * (size_t)zsBias;
  if (gather) gather += (size_t)z * (size_t)zsGather;
  int Meff = M;
  if (countPtr) { int cc = countPtr[z]; if (cc < Meff) Meff = cc; }
  const int row0 = blockIdx.y << 7, col0 = blockIdx.x << 7;
  if (row0 >= Meff) return;
  const int tid = threadIdx.x;
  const int tx = tid & 15, ty = tid >> 4;
  const int r0 = ty << 2, c0 = tx << 2;

  // staging index map (each thread stages 2 float4 of A, 2 float4 of B)
  const int am0 = tid >> 2, ak0 = (tid & 3) << 2;   // A: rows 0..63
  const int am1 = am0 + 64, ak1 = ak0;              //    rows 64..127
  const int bk0 = tid >> 5, bn0 = (tid & 31) << 2;  // B: k-rows 0..7
  const int bk1 = bk0 + 8,  bn1 = bn0;              //    k-rows 8..15

  const int ag0 = row0 + am0, ag1 = row0 + am1;
  const float* aP0 = nullptr; const float* aP1 = nullptr;
  if (ag0 < Meff) aP0 = A + (size_t)(gather ? gather[ag0] : ag0) * lda + ak0;
  if (ag1 < Meff) aP1 = A + (size_t)(gather ? gather[ag1] : ag1) * lda + ak1;
  const float* bP0 = B + (size_t)bk0 * ldb + col0 + bn0;
  const float* bP1 = B + (size_t)bk1 * ldb + col0 + bn1;

  const float4 z4 = make_float4(0.f, 0.f, 0.f, 0.f);
  // prologue: tile 0 -> registers
  float4 aR0 = aP0 ? *(const float4*)aP0 : z4;
  float4 aR1 = aP1 ? *(const float4*)aP1 : z4;
  float4 bR0 = *(const float4*)bP0;
  float4 bR1 = *(const float4*)bP1;

  float acc[8][8];
#pragma unroll
  for (int i = 0; i < 8; ++i)
#pragma unroll
    for (int j = 0; j < 8; ++j) acc[i][j] = 0.f;

  for (int k0 = 0; k0 < K; k0 += 16) {
    // write staged regs -> LDS (A transposed to k-major)
    As[ak0 + 0][am0] = aR0.x; As[ak0 + 1][am0] = aR0.y;
    As[ak0 + 2][am0] = aR0.z; As[ak0 + 3][am0] = aR0.w;
    As[ak1 + 0][am1] = aR1.x; As[ak1 + 1][am1] = aR1.y;
    As[ak1 + 2][am1] = aR1.z; As[ak1 + 3][am1] = aR1.w;
    *(float4*)&Bs[bk0][bn0] = bR0;
    *(float4*)&Bs[bk1][bn1] = bR1;
    __syncthreads();
    // issue next tile's global loads; they fly during the FMA block below
    const int kn = k0 + 16;
    if (kn < K) {
      aR0 = aP0 ? *(const float4*)(aP0 + kn) : z4;
      aR1 = aP1 ? *(const float4*)(aP1 + kn) : z4;
      bR0 = *(const float4*)(bP0 + (size_t)kn * ldb);
      bR1 = *(const float4*)(bP1 + (size_t)kn * ldb);
    }
#pragma unroll
    for (int kk = 0; kk < 16; ++kk) {
      const float4 A0 = *(const float4*)&As[kk][r0];
      const float4 A1 = *(const float4*)&As[kk][r0 + 64];
      const float4 B0 = *(const float4*)&Bs[kk][c0];
      const float4 B1 = *(const float4*)&Bs[kk][c0 + 64];
      const float a[8] = {A0.x, A0.y, A0.z, A0.w, A1.x, A1.y, A1.z, A1.w};
      const float b[8] = {B0.x, B0.y, B0.z, B0.w, B1.x, B1.y, B1.z, B1.w};
#pragma unroll
      for (int i = 0; i < 8; ++i)
#pragma unroll
        for (int j = 0; j < 8; ++j) acc[i][j] = fmaf(a[i], b[j], acc[i][j]);
    }
    __syncthreads();
  }

#pragma unroll
  for (int ih = 0; ih < 2; ++ih) {
#pragma unroll
    for (int i = 0; i < 4; ++i) {
      int gr = row0 + r0 + ih * 64 + i;
      if (gr >= Meff) continue;
      float* crow = Cm + (size_t)gr * ldc + col0;
#pragma unroll
      for (int jh = 0; jh < 2; ++jh) {
        int cc = c0 + jh * 64;
        float4 v;
        v.x = acc[ih * 4 + i][jh * 4 + 0];
        v.y = acc[ih * 4 + i][jh * 4 + 1];
        v.z = acc[ih * 4 + i][jh * 4 + 2];
        v.w = acc[ih * 4 + i][jh * 4 + 3];
        if (bias) {
          v.x += bias[col0 + cc + 0]; v.y += bias[col0 + cc + 1];
          v.z += bias[col0 + cc + 2]; v.w += bias[col0 + cc + 3];
        }
        if (flags & 1) {
          v.x = fmaxf(v.x, 0.f); v.y = fmaxf(v.y, 0.f);
          v.z = fmaxf(v.z, 0.f); v.w = fmaxf(v.w, 0.f);
        }
        if (flags & 2) {
          float4 o = *(const float4*)&crow[cc];
          v.x += o.x; v.y += o.y; v.z += o.z; v.w += o.w;
        }
        *(float4*)&crow[cc] = v;
      }
    }
  }
}

// ---------------- attention: flash-style, fp32, no mask ----------------
// block = (t-tile of 32 rows) x head x batch; online softmax over s-tiles of 64
__global__ __launch_bounds__(256) void k_attn(const float* __restrict__ qkv,
                                              float* __restrict__ o) {
  const int t0 = blockIdx.x * 32;
  const int h = blockIdx.y;
  const int b = blockIdx.z;
  __shared__ float Qs[32][64];
  __shared__ float Ks[64][65];
  __shared__ float Vs[64][65];
  __shared__ float Ss[32][65];
  __shared__ float Ms[32], Ls[32];
  const int tid = threadIdx.x;
  for (int idx = tid; idx < 32 * 16; idx += 256) {
    int r = idx >> 4, d4 = (idx & 15) << 2;
    const float* src = qkv + ((size_t)(b * TSEQ + t0 + r) * 3 + 0) * CDIM + h * DHEAD + d4;
    float4 q = *(const float4*)src;
    Qs[r][d4 + 0] = q.x * 0.125f; Qs[r][d4 + 1] = q.y * 0.125f;  // /sqrt(64) exact
    Qs[r][d4 + 2] = q.z * 0.125f; Qs[r][d4 + 3] = q.w * 0.125f;
  }
  if (tid < 32) { Ms[tid] = -INFINITY; Ls[tid] = 0.f; }
  float Oa[8] = {0, 0, 0, 0, 0, 0, 0, 0};
  const int r = tid >> 3;   // row owned by this thread (8 threads/row, same wave)
  const int dl = tid & 7;
  __syncthreads();
  for (int s0 = 0; s0 < TSEQ; s0 += 64) {
    for (int idx = tid; idx < 64 * 16; idx += 256) {
      int j = idx >> 4, d4 = (idx & 15) << 2;
      const float* kp = qkv + ((size_t)(b * TSEQ + s0 + j) * 3 + 1) * CDIM + h * DHEAD + d4;
      float4 kk = *(const float4*)kp;
      Ks[j][d4 + 0] = kk.x; Ks[j][d4 + 1] = kk.y; Ks[j][d4 + 2] = kk.z; Ks[j][d4 + 3] = kk.w;
      const float* vp = qkv + ((size_t)(b * TSEQ + s0 + j) * 3 + 2) * CDIM + h * DHEAD + d4;
      float4 vv = *(const float4*)vp;
      Vs[j][d4 + 0] = vv.x; Vs[j][d4 + 1] = vv.y; Vs[j][d4 + 2] = vv.z; Vs[j][d4 + 3] = vv.w;
    }
    __syncthreads();
    {  // scores S = (Q/8) @ K^T
      const int j = tid & 63;
      const int r4 = tid >> 6;
#pragma unroll
      for (int i = 0; i < 8; i++) {
        int rr = r4 + (i << 2);
        float acc = 0.f;
#pragma unroll
        for (int d = 0; d < 64; d++) acc += Qs[rr][d] * Ks[j][d];
        Ss[rr][j] = acc;
      }
    }
    __syncthreads();
    // online softmax update (8 threads per row, within one wave)
    float mloc = -INFINITY;
#pragma unroll
    for (int i = 0; i < 8; i++) mloc = fmaxf(mloc, Ss[r][dl + (i << 3)]);
#pragma unroll
    for (int off = 4; off > 0; off >>= 1) mloc = fmaxf(mloc, __shfl_xor(mloc, off, 8));
    float mold = Ms[r];
    float mnew = fmaxf(mold, mloc);
    float alpha = expf(mold - mnew);
    float psum = 0.f;
#pragma unroll
    for (int i = 0; i < 8; i++) {
      int j = dl + (i << 3);
      float p = expf(Ss[r][j] - mnew);
      Ss[r][j] = p;
      psum += p;
    }
#pragma unroll
    for (int off = 4; off > 0; off >>= 1) psum += __shfl_xor(psum, off, 8);
    if (dl == 0) { Ms[r] = mnew; Ls[r] = Ls[r] * alpha + psum; }
#pragma unroll
    for (int i = 0; i < 8; i++) Oa[i] *= alpha;
    for (int j = 0; j < 64; j++) {
      float p = Ss[r][j];
#pragma unroll
      for (int i = 0; i < 8; i++) Oa[i] += p * Vs[j][(dl << 3) + i];
    }
    __syncthreads();
  }
  float linv = 1.0f / Ls[r];
  float* op = o + (size_t)(b * TSEQ + t0 + r) * CDIM + h * DHEAD + (dl << 3);
#pragma unroll
  for (int i = 0; i < 8; i++) op[i] = Oa[i] * linv;
}

// ---------------- router: logits + threefry noise + top-2 ----------------
__global__ __launch_bounds__(256) void k_route(
    const float* __restrict__ xn,
    const float* __restrict__ rw, const float* __restrict__ rb,
    const float* __restrict__ nw, const float* __restrict__ nb,
    int layer, int* __restrict__ topi, float* __restrict__ gate) {
  int token = blockIdx.x, tid = threadIdx.x;
  float acc[16];
#pragma unroll
  for (int j = 0; j < 16; j++) acc[j] = 0.f;
  const float* xr = xn + (size_t)token * CDIM;
  for (int c = tid; c < CDIM; c += 256) {
    float xc = xr[c];
    const float* w1p = rw + (size_t)c * NEXP;
    const float* w2p = nw + (size_t)c * NEXP;
#pragma unroll
    for (int j = 0; j < 8; j++) acc[j] += xc * w1p[j];
#pragma unroll
    for (int j = 0; j < 8; j++) acc[8 + j] += xc * w2p[j];
  }
#pragma unroll
  for (int j = 0; j < 16; j++) {
#pragma unroll
    for (int off = 32; off > 0; off >>= 1) acc[j] += __shfl_xor(acc[j], off, 64);
  }
  __shared__ float wp[4][16];
  int wid = tid >> 6;
  if ((tid & 63) == 0) {
#pragma unroll
    for (int j = 0; j < 16; j++) wp[wid][j] = acc[j];
  }
  __syncthreads();
  __shared__ float noisy[8];
  if (tid < 8) {
    int j = tid;
    float logit = wp[0][j] + wp[1][j] + wp[2][j] + wp[3][j] + rb[j];
    float nl = wp[0][8 + j] + wp[1][8 + j] + wp[2][8 + j] + wp[3][8 + j] + nb[j];
    float sp = fmaxf(nl, 0.f) + log1pf(expf(-fabsf(nl)));  // softplus
    // key_l = fold_in(key(42), layer) = threefry((0,42),(0,layer))
    uint32_t k0, k1, o0, o1;
    threefry2x32(0u, 42u, 0u, (uint32_t)layer, k0, k1);
    // partitionable random_bits: counter = (0, i), bits = o0 ^ o1
    uint32_t idx = (uint32_t)(token * NEXP + j);
    threefry2x32(k0, k1, 0u, idx, o0, o1);
    uint32_t bits = o0 ^ o1;
    float f = __uint_as_float((bits >> 9) | 0x3f800000u) - 1.0f;  // [0,1)
    const float lo = -0.99999994f;  // nextafter(-1,0); (hi-lo) rounds to 2.0f
    float u = fmaxf(lo, f * 2.0f + lo);
    float z = 1.41421356f * erfinv_f32(u);
    noisy[j] = logit + z * sp;
  }
  __syncthreads();
  if (tid == 0) {
    float v1 = -INFINITY; int i1 = 0;
#pragma unroll
    for (int j = 0; j < 8; j++) { float v = noisy[j]; if (v > v1) { v1 = v; i1 = j; } }
    float v2 = -INFINITY; int i2 = 0;
#pragma unroll
    for (int j = 0; j < 8; j++) {
      if (j == i1) continue;
      float v = noisy[j]; if (v > v2) { v2 = v; i2 = j; }
    }
    float e2 = expf(v2 - v1);
    float denom = 1.0f + e2;
    topi[token * 2] = i1; topi[token * 2 + 1] = i2;
    gate[token * 2] = 1.0f / denom;
    gate[token * 2 + 1] = e2 / denom;
  }
}

// ---------------- per-expert capacity scan (stable token order) ----------------
__global__ __launch_bounds__(256) void k_scan(const int* __restrict__ topi,
    int* __restrict__ perm, int* __restrict__ slot, int* __restrict__ count) {
  int e = blockIdx.x, tid = threadIdx.x;
  __shared__ int ps[256];
  __shared__ int sbase;
  if (tid == 0) sbase = 0;
  __syncthreads();
  for (int c0 = 0; c0 < NTOK; c0 += 256) {
    int token = c0 + tid;
    int j0 = topi[token * 2], j1 = topi[token * 2 + 1];
    int flag = (j0 == e || j1 == e) ? 1 : 0;
    ps[tid] = flag;
    __syncthreads();
    for (int off = 1; off < 256; off <<= 1) {
      int v = (tid >= off) ? ps[tid - off] : 0;
      __syncthreads();
      ps[tid] += v;
      __syncthreads();
    }
    int pos = sbase + ps[tid] - flag;  // exclusive prefix
    if (flag) {
      int s = (pos < ECAP) ? pos : -1;
      if (s >= 0) perm[e * ECAP + s] = token;
      if (j0 == e) slot[token * 2] = s;
      else slot[token * 2 + 1] = s;
    }
    __syncthreads();
    if (tid == 0) sbase += ps[255];
    __syncthreads();
  }
  if (tid == 0) count[e] = (sbase < ECAP) ? sbase : ECAP;
}

// ---------------- token-side gather of expert outputs, add into x ----------------
__global__ __launch_bounds__(256) void k_moe_add(
    const float* __restrict__ ybuf,
    const int* __restrict__ topi, const int* __restrict__ slot,
    const float* __restrict__ gate, float* __restrict__ x) {
  int token = blockIdx.x, tid = threadIdx.x;
  int e0 = topi[token * 2], s0 = slot[token * 2];
  int e1 = topi[token * 2 + 1], s1 = slot[token * 2 + 1];
  float g0 = gate[token * 2], g1 = gate[token * 2 + 1];
  const float* y0 = ybuf + ((size_t)e0 * ECAP + (s0 < 0 ? 0 : s0)) * CDIM;
  const float* y1 = ybuf + ((size_t)e1 * ECAP + (s1 < 0 ? 0 : s1)) * CDIM;
  float* xr = x + (size_t)token * CDIM;
  for (int c = tid; c < CDIM; c += 256) {
    float v = xr[c];
    if (s0 >= 0) v += g0 * y0[c];
    if (s1 >= 0) v += g1 * y1[c];
    xr[c] = v;
  }
}

// ---------------- head: out = xn @ head_w + head_b ----------------
__global__ __launch_bounds__(256) void k_head(const float* __restrict__ xn,
    const float* __restrict__ hw, const float* __restrict__ hb,
    float* __restrict__ out) {
  __shared__ float red[256];
  int token = blockIdx.x, tid = threadIdx.x;
  const float* xr = xn + (size_t)token * CDIM;
  float s = 0.f;
  for (int c = tid; c < CDIM; c += 256) s += xr[c] * hw[c];
  red[tid] = s; __syncthreads();
  for (int off = 128; off > 0; off >>= 1) {
    if (tid < off) red[tid] += red[tid + off];
    __syncthreads();
  }
  if (tid == 0) out[token] = red[0] + hb[0];
}

extern "C" void kernel_launch(void* const* d_in, const int* in_sizes, int n_in,
                              void* d_out, int out_size, void* d_ws, size_t ws_size,
                              hipStream_t stream) {
  const int* ids = (const int*)d_in[0];
  const float* tok_emb = (const float*)d_in[1];
  const float* pos_emb = (const float*)d_in[2];
  const float* ln1_g = (const float*)d_in[3];
  const float* ln1_b = (const float*)d_in[4];
  const float* ln2_g = (const float*)d_in[5];
  const float* ln2_b = (const float*)d_in[6];
  const float* qkv_w = (const float*)d_in[7];
  const float* out_w = (const float*)d_in[8];
  const float* route_w = (const float*)d_in[9];
  const float* route_b = (const float*)d_in[10];
  const float* noise_w = (const float*)d_in[11];
  const float* noise_b = (const float*)d_in[12];
  const float* w1 = (const float*)d_in[13];
  const float* b1 = (const float*)d_in[14];
  const float* w2 = (const float*)d_in[15];
  const float* b2 = (const float*)d_in[16];
  const float* lnf_g = (const float*)d_in[17];
  const float* lnf_b = (const float*)d_in[18];
  const float* head_w = (const float*)d_in[19];
  const float* head_b = (const float*)d_in[20];
  float* out = (float*)d_out;

  const size_t MB = 1024u * 1024u;
  char* ws = (char*)d_ws;
  // Big path: batch all 8 experts' h-activations (128 MB) so one launch
  // covers the whole MoE FFN. Needs 192 MB + small region.
  const bool big = ws_size >= (size_t)194 * MB;

  float* x    = (float*)(ws);              // 16MB: residual stream
  float* xn   = (float*)(ws + 16 * MB);    // 16MB: LN out / attn out (o)
  float* qkv  = (float*)(ws + 32 * MB);    // 48MB (dead after k_attn)
  float* hbuf = (float*)(ws + 32 * MB);    // aliases qkv; 16MB (small) / 128MB (big)
  float* ybuf = big ? (float*)(ws + 160 * MB)   // 32MB
                    : (float*)(ws + 48 * MB);   // 32MB
  char* small = big ? (ws + 192 * MB) : (ws + 80 * MB);
  int* topi = (int*)small;                 // 2*NTOK ints
  int* slot = topi + 2 * NTOK;             // 2*NTOK ints
  float* gate = (float*)(slot + 2 * NTOK); // 2*NTOK floats
  int* perm = (int*)(gate + 2 * NTOK);     // NEXP*ECAP ints
  int* count = perm + NEXP * ECAP;         // NEXP ints

  k_embed<<<NTOK, 256, 0, stream>>>(ids, tok_emb, pos_emb, x);

  for (int l = 0; l < 2; l++) {
    k_ln<<<NTOK, 256, 0, stream>>>(x, xn, ln1_g + l * CDIM, ln1_b + l * CDIM);
    // qkv = xn @ qkv_w[l]   (4096 x 3072 x 1024)
    k_gemm<<<dim3(3 * CDIM / 128, NTOK / 128, 1), 256, 0, stream>>>(xn, CDIM,
        qkv_w + (size_t)l * CDIM * 3 * CDIM, 3 * CDIM, qkv, 3 * CDIM,
        NTOK, 3 * CDIM, CDIM, nullptr, nullptr, nullptr, 0,
        0, 0, 0, 0, 0);
    // attention -> o (into xn region)
    k_attn<<<dim3(TSEQ / 32, NHEAD, 2), 256, 0, stream>>>(qkv, xn);
    // x += o @ out_w[l]
    k_gemm<<<dim3(CDIM / 128, NTOK / 128, 1), 256, 0, stream>>>(xn, CDIM,
        out_w + (size_t)l * CDIM * CDIM, CDIM, x, CDIM,
        NTOK, CDIM, CDIM, nullptr, nullptr, nullptr, 2,
        0, 0, 0, 0, 0);
    // ln2 -> xn
    k_ln<<<NTOK, 256, 0, stream>>>(x, xn, ln2_g + l * CDIM, ln2_b + l * CDIM);
    // router
    k_route<<<NTOK, 256, 0, stream>>>(xn,
        route_w + (size_t)l * CDIM * NEXP, route_b + l * NEXP,
        noise_w + (size_t)l * CDIM * NEXP, noise_b + l * NEXP,
        l, topi, gate);
    k_scan<<<NEXP, 256, 0, stream>>>(topi, perm, slot, count);
    // expert FFNs
    if (big) {
      // h = relu(xn[perm_e] @ w1_e + b1_e) for all 8 experts in one launch
      k_gemm<<<dim3(HIDN / 128, ECAP / 128, NEXP), 256, 0, stream>>>(xn, CDIM,
          w1 + (size_t)l * NEXP * CDIM * HIDN, HIDN, hbuf, HIDN,
          ECAP, HIDN, CDIM, b1 + (size_t)l * NEXP * HIDN, perm, count, 1,
          0, (size_t)CDIM * HIDN, (size_t)ECAP * HIDN, HIDN, ECAP);
      // y = h_e @ w2_e + b2_e for all 8 experts in one launch
      k_gemm<<<dim3(CDIM / 128, ECAP / 128, NEXP), 256, 0, stream>>>(hbuf, HIDN,
          w2 + (size_t)l * NEXP * HIDN * CDIM, CDIM, ybuf, CDIM,
          ECAP, CDIM, HIDN, b2 + (size_t)l * NEXP * CDIM, nullptr, count, 0,
          (size_t)ECAP * HIDN, (size_t)HIDN * CDIM, (size_t)ECAP * CDIM, CDIM, 0);
    } else {
      for (int e = 0; e < NEXP; e++) {
        const size_t we = (size_t)(l * NEXP + e);
        k_gemm<<<dim3(HIDN / 128, ECAP / 128, 1), 256, 0, stream>>>(xn, CDIM,
            w1 + we * CDIM * HIDN, HIDN, hbuf, HIDN,
            ECAP, HIDN, CDIM, b1 + we * HIDN, perm + e * ECAP, count + e, 1,
            0, 0, 0, 0, 0);
        k_gemm<<<dim3(CDIM / 128, ECAP / 128, 1), 256, 0, stream>>>(hbuf, HIDN,
            w2 + we * HIDN * CDIM, CDIM, ybuf + (size_t)e * ECAP * CDIM, CDIM,
            ECAP, CDIM, HIDN, b2 + we * CDIM, nullptr, count + e, 0,
            0, 0, 0, 0, 0);
      }
    }
    k_moe_add<<<NTOK, 256, 0, stream>>>(ybuf, topi, slot, gate, x);
  }

  k_ln<<<NTOK, 256, 0, stream>>>(x, xn, lnf_g, lnf_b);
  k_head<<<NTOK, 256, 0, stream>>>(xn, head_w, head_b, out);
}

// Round 2
// 5855.956 us; speedup vs baseline: 2.4092x; 1.3875x over previous
//
#include <hip/hip_runtime.h>
#include <stdint.h>
#include <math.h>

// Problem constants
#define NTOK 4096   // B*T
#define TSEQ 2048
#define CDIM 1024
#define NHEAD 16
#define DHEAD 64
#define NEXP 8
#define HIDN 4096
#define ECAP 1024

// ---------------- threefry2x32 (exact JAX semantics) ----------------
__device__ __forceinline__ void threefry2x32(uint32_t k0, uint32_t k1,
                                             uint32_t x0, uint32_t x1,
                                             uint32_t& o0, uint32_t& o1) {
  uint32_t ks2 = k0 ^ k1 ^ 0x1BD11BDAu;
#define TF_R(r) { x0 += x1; x1 = (x1 << (r)) | (x1 >> (32 - (r))); x1 ^= x0; }
  x0 += k0; x1 += k1;
  TF_R(13) TF_R(15) TF_R(26) TF_R(6)
  x0 += k1; x1 += ks2 + 1u;
  TF_R(17) TF_R(29) TF_R(16) TF_R(24)
  x0 += ks2; x1 += k0 + 2u;
  TF_R(13) TF_R(15) TF_R(26) TF_R(6)
  x0 += k0; x1 += k1 + 3u;
  TF_R(17) TF_R(29) TF_R(16) TF_R(24)
  x0 += k1; x1 += ks2 + 4u;
  TF_R(13) TF_R(15) TF_R(26) TF_R(6)
  x0 += ks2; x1 += k0 + 5u;
#undef TF_R
  o0 = x0; o1 = x1;
}

// XLA's f32 erf_inv (Giles 2012 polynomial, log1p variant)
__device__ __forceinline__ float erfinv_f32(float x) {
  float w = -log1pf(-x * x);
  float p;
  if (w < 5.0f) {
    w = w - 2.5f;
    p = 2.81022636e-08f;
    p = fmaf(p, w, 3.43273939e-07f);
    p = fmaf(p, w, -3.5233877e-06f);
    p = fmaf(p, w, -4.39150654e-06f);
    p = fmaf(p, w, 0.00021858087f);
    p = fmaf(p, w, -0.00125372503f);
    p = fmaf(p, w, -0.00417768164f);
    p = fmaf(p, w, 0.246640727f);
    p = fmaf(p, w, 1.50140941f);
  } else {
    w = sqrtf(w) - 3.0f;
    p = -0.000200214257f;
    p = fmaf(p, w, 0.000100950558f);
    p = fmaf(p, w, 0.00134934322f);
    p = fmaf(p, w, -0.00367342844f);
    p = fmaf(p, w, 0.00573950773f);
    p = fmaf(p, w, -0.0076224613f);
    p = fmaf(p, w, 0.00943887047f);
    p = fmaf(p, w, 1.00167406f);
    p = fmaf(p, w, 2.83297682f);
  }
  return p * x;
}

// ---------------- embedding ----------------
__global__ __launch_bounds__(256) void k_embed(const int* __restrict__ ids,
    const float* __restrict__ tok, const float* __restrict__ pos,
    float* __restrict__ x) {
  int row = blockIdx.x;
  int id = ids[row];
  int t = row & (TSEQ - 1);
  const float* tr = tok + (size_t)id * CDIM;
  const float* pr = pos + (size_t)t * CDIM;
  float* xr = x + (size_t)row * CDIM;
  for (int c = threadIdx.x; c < CDIM; c += 256) xr[c] = tr[c] + pr[c];
}

// ---------------- layernorm (two-pass, matches jnp.var) ----------------
__global__ __launch_bounds__(256) void k_ln(const float* __restrict__ in,
    float* __restrict__ out, const float* __restrict__ g, const float* __restrict__ b) {
  __shared__ float red[256];
  int row = blockIdx.x, tid = threadIdx.x;
  const float* xr = in + (size_t)row * CDIM;
  float s = 0.f;
  for (int c = tid; c < CDIM; c += 256) s += xr[c];
  red[tid] = s; __syncthreads();
  for (int off = 128; off > 0; off >>= 1) {
    if (tid < off) red[tid] += red[tid + off];
    __syncthreads();
  }
  float m = red[0] * (1.0f / CDIM);
  __syncthreads();
  float v = 0.f;
  for (int c = tid; c < CDIM; c += 256) { float d = xr[c] - m; v += d * d; }
  red[tid] = v; __syncthreads();
  for (int off = 128; off > 0; off >>= 1) {
    if (tid < off) red[tid] += red[tid + off];
    __syncthreads();
  }
  float var = red[0] * (1.0f / CDIM);
  float rstd = 1.0f / sqrtf(var + 1e-5f);
  float* orow = out + (size_t)row * CDIM;
  for (int c = tid; c < CDIM; c += 256)
    orow[c] = (xr[c] - m) * rstd * g[c] + b[c];
}

// ---------------- high-throughput tiled fp32 GEMM ----------------
// 128x128 tile per 256-thread block, 8x8 per thread, BK=16, k-major LDS,
// register-prefetch pipeline. Optional per-z (blockIdx.z) batching via
// element strides (expert batching). C[M,N] (flags&2: +=) =
// act( A[gather?][K] @ B[K,N] + bias ); flags&1: relu.
// countPtr[z]: Meff = min(M, count) row limit (device-side).
__global__ __launch_bounds__(256, 2) void k_gemm(
    const float* __restrict__ A, int lda,
    const float* __restrict__ B, int ldb,
    float* __restrict__ Cm, int ldc,
    int M, int N, int K,
    const float* __restrict__ bias,
    const int* __restrict__ gather,
    const int* __restrict__ countPtr,
    int flags,
    size_t zsA, size_t zsB, size_t zsC, int zsBias, int zsGather) {
  __shared__ float As[16][132];   // k-major, padded: conflict-free frag reads
  __shared__ float Bs[16][128];   // k-major, rows match global layout
  const int z = blockIdx.z;
  A += (size_t)z * zsA;
  B += (size_t)z * zsB;
  Cm += (size_t)z * zsC;
  if (bias) bias += (size_t)z * (size_t)zsBias;
  if (gather) gather += (size_t)z * (size_t)zsGather;
  int Meff = M;
  if (countPtr) { int cc = countPtr[z]; if (cc < Meff) Meff = cc; }
  const int row0 = blockIdx.y << 7, col0 = blockIdx.x << 7;
  if (row0 >= Meff) return;
  const int tid = threadIdx.x;
  const int tx = tid & 15, ty = tid >> 4;
  const int r0 = ty << 2, c0 = tx << 2;

  // staging index map (each thread stages 2 float4 of A, 2 float4 of B)
  const int am0 = tid >> 2, ak0 = (tid & 3) << 2;   // A: rows 0..63
  const int am1 = am0 + 64, ak1 = ak0;              //    rows 64..127
  const int bk0 = tid >> 5, bn0 = (tid & 31) << 2;  // B: k-rows 0..7
  const int bk1 = bk0 + 8,  bn1 = bn0;              //    k-rows 8..15

  const int ag0 = row0 + am0, ag1 = row0 + am1;
  const float* aP0 = nullptr; const float* aP1 = nullptr;
  if (ag0 < Meff) aP0 = A + (size_t)(gather ? gather[ag0] : ag0) * lda + ak0;
  if (ag1 < Meff) aP1 = A + (size_t)(gather ? gather[ag1] : ag1) * lda + ak1;
  const float* bP0 = B + (size_t)bk0 * ldb + col0 + bn0;
  const float* bP1 = B + (size_t)bk1 * ldb + col0 + bn1;

  const float4 z4 = make_float4(0.f, 0.f, 0.f, 0.f);
  // prologue: tile 0 -> registers
  float4 aR0 = aP0 ? *(const float4*)aP0 : z4;
  float4 aR1 = aP1 ? *(const float4*)aP1 : z4;
  float4 bR0 = *(const float4*)bP0;
  float4 bR1 = *(const float4*)bP1;

  float acc[8][8];
#pragma unroll
  for (int i = 0; i < 8; ++i)
#pragma unroll
    for (int j = 0; j < 8; ++j) acc[i][j] = 0.f;

  for (int k0 = 0; k0 < K; k0 += 16) {
    // write staged regs -> LDS (A transposed to k-major)
    As[ak0 + 0][am0] = aR0.x; As[ak0 + 1][am0] = aR0.y;
    As[ak0 + 2][am0] = aR0.z; As[ak0 + 3][am0] = aR0.w;
    As[ak1 + 0][am1] = aR1.x; As[ak1 + 1][am1] = aR1.y;
    As[ak1 + 2][am1] = aR1.z; As[ak1 + 3][am1] = aR1.w;
    *(float4*)&Bs[bk0][bn0] = bR0;
    *(float4*)&Bs[bk1][bn1] = bR1;
    __syncthreads();
    // issue next tile's global loads; they fly during the FMA block below
    const int kn = k0 + 16;
    if (kn < K) {
      aR0 = aP0 ? *(const float4*)(aP0 + kn) : z4;
      aR1 = aP1 ? *(const float4*)(aP1 + kn) : z4;
      bR0 = *(const float4*)(bP0 + (size_t)kn * ldb);
      bR1 = *(const float4*)(bP1 + (size_t)kn * ldb);
    }
#pragma unroll
    for (int kk = 0; kk < 16; ++kk) {
      const float4 A0 = *(const float4*)&As[kk][r0];
      const float4 A1 = *(const float4*)&As[kk][r0 + 64];
      const float4 B0 = *(const float4*)&Bs[kk][c0];
      const float4 B1 = *(const float4*)&Bs[kk][c0 + 64];
      const float a[8] = {A0.x, A0.y, A0.z, A0.w, A1.x, A1.y, A1.z, A1.w};
      const float b[8] = {B0.x, B0.y, B0.z, B0.w, B1.x, B1.y, B1.z, B1.w};
#pragma unroll
      for (int i = 0; i < 8; ++i)
#pragma unroll
        for (int j = 0; j < 8; ++j) acc[i][j] = fmaf(a[i], b[j], acc[i][j]);
    }
    __syncthreads();
  }

#pragma unroll
  for (int ih = 0; ih < 2; ++ih) {
#pragma unroll
    for (int i = 0; i < 4; ++i) {
      int gr = row0 + r0 + ih * 64 + i;
      if (gr >= Meff) continue;
      float* crow = Cm + (size_t)gr * ldc + col0;
#pragma unroll
      for (int jh = 0; jh < 2; ++jh) {
        int cc = c0 + jh * 64;
        float4 v;
        v.x = acc[ih * 4 + i][jh * 4 + 0];
        v.y = acc[ih * 4 + i][jh * 4 + 1];
        v.z = acc[ih * 4 + i][jh * 4 + 2];
        v.w = acc[ih * 4 + i][jh * 4 + 3];
        if (bias) {
          v.x += bias[col0 + cc + 0]; v.y += bias[col0 + cc + 1];
          v.z += bias[col0 + cc + 2]; v.w += bias[col0 + cc + 3];
        }
        if (flags & 1) {
          v.x = fmaxf(v.x, 0.f); v.y = fmaxf(v.y, 0.f);
          v.z = fmaxf(v.z, 0.f); v.w = fmaxf(v.w, 0.f);
        }
        if (flags & 2) {
          float4 o = *(const float4*)&crow[cc];
          v.x += o.x; v.y += o.y; v.z += o.z; v.w += o.w;
        }
        *(float4*)&crow[cc] = v;
      }
    }
  }
}

// ---------------- attention: flash-style, register-blocked GEMM phases ----------------
// Block: 128 Q-rows x (head, batch). s-tiles of 64 keys. 256 threads.
// Phase A: S = Q@K^T (8x4/thread), phase B: in-register online softmax,
// phase C: O += P@V (8x4/thread). K transposed at stage (stride 66),
// Q/P d-major (stride 132), V natural (stride 68). ~99.5 KB LDS -> 1 block/CU.
__global__ __launch_bounds__(256, 1) void k_attn(const float* __restrict__ qkv,
                                                 float* __restrict__ o) {
  __shared__ float Qs[64][132];  // Qs[d][r], scaled by 1/8
  __shared__ float Ks[64][66];   // Ks[d][j]  (stride 66: b64 reads, 4-way stage writes)
  __shared__ float Vs[64][68];   // Vs[j][d]
  __shared__ float Ps[64][132];  // Ps[j][r]
  const int t0 = blockIdx.x << 7;
  const int h = blockIdx.y;
  const int b = blockIdx.z;
  const int tid = threadIdx.x;
  const int tx = tid & 15, ty = tid >> 4;
  const int r0 = ty << 2;   // rows r0..r0+3 and r0+64..r0+67
  const int c0 = tx << 2;   // cols c0..c0+3

  // ---- load Q tile (128 x 64), scale, store transposed (d-major)
#pragma unroll
  for (int p = 0; p < 8; ++p) {
    int idx = tid + (p << 8);
    int r = idx >> 4, d4 = (idx & 15) << 2;
    const float4 q = *(const float4*)(qkv +
        ((size_t)(b * TSEQ + t0 + r) * 3 + 0) * CDIM + h * DHEAD + d4);
    Qs[d4 + 0][r] = q.x * 0.125f;
    Qs[d4 + 1][r] = q.y * 0.125f;
    Qs[d4 + 2][r] = q.z * 0.125f;
    Qs[d4 + 3][r] = q.w * 0.125f;
  }

  float m0[8], l0[8], Oacc[8][4];
#pragma unroll
  for (int i = 0; i < 8; ++i) {
    m0[i] = -INFINITY; l0[i] = 0.f;
#pragma unroll
    for (int j = 0; j < 4; ++j) Oacc[i][j] = 0.f;
  }

  // prologue: prefetch K/V tile 0 into registers
  float4 kreg[4], vreg[4];
#pragma unroll
  for (int p = 0; p < 4; ++p) {
    int idx = tid + (p << 8);
    int j = idx >> 4, d4 = (idx & 15) << 2;
    kreg[p] = *(const float4*)(qkv + ((size_t)(b * TSEQ + j) * 3 + 1) * CDIM + h * DHEAD + d4);
    vreg[p] = *(const float4*)(qkv + ((size_t)(b * TSEQ + j) * 3 + 2) * CDIM + h * DHEAD + d4);
  }

  for (int s0 = 0; s0 < TSEQ; s0 += 64) {
    // write staged K (transposed) and V tiles to LDS
#pragma unroll
    for (int p = 0; p < 4; ++p) {
      int idx = tid + (p << 8);
      int j = idx >> 4, d4 = (idx & 15) << 2;
      Ks[d4 + 0][j] = kreg[p].x;
      Ks[d4 + 1][j] = kreg[p].y;
      Ks[d4 + 2][j] = kreg[p].z;
      Ks[d4 + 3][j] = kreg[p].w;
      *(float4*)&Vs[j][d4] = vreg[p];
    }
    __syncthreads();
    // prefetch next s-tile (hidden under phases A-C)
    if (s0 + 64 < TSEQ) {
#pragma unroll
      for (int p = 0; p < 4; ++p) {
        int idx = tid + (p << 8);
        int j = idx >> 4, d4 = (idx & 15) << 2;
        kreg[p] = *(const float4*)(qkv + ((size_t)(b * TSEQ + s0 + 64 + j) * 3 + 1) * CDIM + h * DHEAD + d4);
        vreg[p] = *(const float4*)(qkv + ((size_t)(b * TSEQ + s0 + 64 + j) * 3 + 2) * CDIM + h * DHEAD + d4);
      }
    }
    // ---- phase A: S = Q @ K^T (8x4 per thread)
    float sacc[8][4];
#pragma unroll
    for (int i = 0; i < 8; ++i)
#pragma unroll
      for (int j = 0; j < 4; ++j) sacc[i][j] = 0.f;
#pragma unroll 8
    for (int kk = 0; kk < 64; ++kk) {
      const float4 qa = *(const float4*)&Qs[kk][r0];
      const float4 qb = *(const float4*)&Qs[kk][r0 + 64];
      const float2 ka = *(const float2*)&Ks[kk][c0];
      const float2 kb = *(const float2*)&Ks[kk][c0 + 2];
      const float av[8] = {qa.x, qa.y, qa.z, qa.w, qb.x, qb.y, qb.z, qb.w};
      const float bv[4] = {ka.x, ka.y, kb.x, kb.y};
#pragma unroll
      for (int i = 0; i < 8; ++i)
#pragma unroll
        for (int j = 0; j < 4; ++j) sacc[i][j] = fmaf(av[i], bv[j], sacc[i][j]);
    }
    // ---- phase B: online softmax (row = 16 contiguous lanes), write P
    float pv[8][4];
#pragma unroll
    for (int i = 0; i < 8; ++i) {
      float mx = fmaxf(fmaxf(sacc[i][0], sacc[i][1]), fmaxf(sacc[i][2], sacc[i][3]));
#pragma unroll
      for (int off = 8; off > 0; off >>= 1) mx = fmaxf(mx, __shfl_xor(mx, off, 16));
      float mnew = fmaxf(m0[i], mx);
      float alpha = expf(m0[i] - mnew);
      float psum = 0.f;
#pragma unroll
      for (int j = 0; j < 4; ++j) {
        float p = expf(sacc[i][j] - mnew);
        pv[i][j] = p;
        psum += p;
      }
#pragma unroll
      for (int off = 8; off > 0; off >>= 1) psum += __shfl_xor(psum, off, 16);
      l0[i] = l0[i] * alpha + psum;
      m0[i] = mnew;
#pragma unroll
      for (int j = 0; j < 4; ++j) Oacc[i][j] *= alpha;
    }
#pragma unroll
    for (int jj = 0; jj < 4; ++jj) {
      *(float4*)&Ps[c0 + jj][r0] =
          make_float4(pv[0][jj], pv[1][jj], pv[2][jj], pv[3][jj]);
      *(float4*)&Ps[c0 + jj][r0 + 64] =
          make_float4(pv[4][jj], pv[5][jj], pv[6][jj], pv[7][jj]);
    }
    __syncthreads();
    // ---- phase C: O += P @ V (8x4 per thread)
#pragma unroll 8
    for (int kk = 0; kk < 64; ++kk) {
      const float4 pa = *(const float4*)&Ps[kk][r0];
      const float4 pb = *(const float4*)&Ps[kk][r0 + 64];
      const float4 vv = *(const float4*)&Vs[kk][c0];
      const float av[8] = {pa.x, pa.y, pa.z, pa.w, pb.x, pb.y, pb.z, pb.w};
      const float bv[4] = {vv.x, vv.y, vv.z, vv.w};
#pragma unroll
      for (int i = 0; i < 8; ++i)
#pragma unroll
        for (int j = 0; j < 4; ++j) Oacc[i][j] = fmaf(av[i], bv[j], Oacc[i][j]);
    }
    __syncthreads();
  }
  // ---- epilogue: normalize and store
#pragma unroll
  for (int i = 0; i < 8; ++i) {
    int r = t0 + ((i < 4) ? (r0 + i) : (r0 + 60 + i));  // second half: +64
    float inv = 1.0f / l0[i];
    float4 v;
    v.x = Oacc[i][0] * inv; v.y = Oacc[i][1] * inv;
    v.z = Oacc[i][2] * inv; v.w = Oacc[i][3] * inv;
    *(float4*)(o + (size_t)(b * TSEQ + r) * CDIM + h * DHEAD + c0) = v;
  }
}

// ---------------- router: logits + threefry noise + top-2 ----------------
__global__ __launch_bounds__(256) void k_route(
    const float* __restrict__ xn,
    const float* __restrict__ rw, const float* __restrict__ rb,
    const float* __restrict__ nw, const float* __restrict__ nb,
    int layer, int* __restrict__ topi, float* __restrict__ gate) {
  int token = blockIdx.x, tid = threadIdx.x;
  float acc[16];
#pragma unroll
  for (int j = 0; j < 16; j++) acc[j] = 0.f;
  const float* xr = xn + (size_t)token * CDIM;
  for (int c = tid; c < CDIM; c += 256) {
    float xc = xr[c];
    const float* w1p = rw + (size_t)c * NEXP;
    const float* w2p = nw + (size_t)c * NEXP;
#pragma unroll
    for (int j = 0; j < 8; j++) acc[j] += xc * w1p[j];
#pragma unroll
    for (int j = 0; j < 8; j++) acc[8 + j] += xc * w2p[j];
  }
#pragma unroll
  for (int j = 0; j < 16; j++) {
#pragma unroll
    for (int off = 32; off > 0; off >>= 1) acc[j] += __shfl_xor(acc[j], off, 64);
  }
  __shared__ float wp[4][16];
  int wid = tid >> 6;
  if ((tid & 63) == 0) {
#pragma unroll
    for (int j = 0; j < 16; j++) wp[wid][j] = acc[j];
  }
  __syncthreads();
  __shared__ float noisy[8];
  if (tid < 8) {
    int j = tid;
    float logit = wp[0][j] + wp[1][j] + wp[2][j] + wp[3][j] + rb[j];
    float nl = wp[0][8 + j] + wp[1][8 + j] + wp[2][8 + j] + wp[3][8 + j] + nb[j];
    float sp = fmaxf(nl, 0.f) + log1pf(expf(-fabsf(nl)));  // softplus
    // key_l = fold_in(key(42), layer) = threefry((0,42),(0,layer))
    uint32_t k0, k1, o0, o1;
    threefry2x32(0u, 42u, 0u, (uint32_t)layer, k0, k1);
    // partitionable random_bits: counter = (0, i), bits = o0 ^ o1
    uint32_t idx = (uint32_t)(token * NEXP + j);
    threefry2x32(k0, k1, 0u, idx, o0, o1);
    uint32_t bits = o0 ^ o1;
    float f = __uint_as_float((bits >> 9) | 0x3f800000u) - 1.0f;  // [0,1)
    const float lo = -0.99999994f;  // nextafter(-1,0); (hi-lo) rounds to 2.0f
    float u = fmaxf(lo, f * 2.0f + lo);
    float z = 1.41421356f * erfinv_f32(u);
    noisy[j] = logit + z * sp;
  }
  __syncthreads();
  if (tid == 0) {
    float v1 = -INFINITY; int i1 = 0;
#pragma unroll
    for (int j = 0; j < 8; j++) { float v = noisy[j]; if (v > v1) { v1 = v; i1 = j; } }
    float v2 = -INFINITY; int i2 = 0;
#pragma unroll
    for (int j = 0; j < 8; j++) {
      if (j == i1) continue;
      float v = noisy[j]; if (v > v2) { v2 = v; i2 = j; }
    }
    float e2 = expf(v2 - v1);
    float denom = 1.0f + e2;
    topi[token * 2] = i1; topi[token * 2 + 1] = i2;
    gate[token * 2] = 1.0f / denom;
    gate[token * 2 + 1] = e2 / denom;
  }
}

// ---------------- per-expert capacity scan (stable token order) ----------------
__global__ __launch_bounds__(256) void k_scan(const int* __restrict__ topi,
    int* __restrict__ perm, int* __restrict__ slot, int* __restrict__ count) {
  int e = blockIdx.x, tid = threadIdx.x;
  __shared__ int ps[256];
  __shared__ int sbase;
  if (tid == 0) sbase = 0;
  __syncthreads();
  for (int c0 = 0; c0 < NTOK; c0 += 256) {
    int token = c0 + tid;
    int j0 = topi[token * 2], j1 = topi[token * 2 + 1];
    int flag = (j0 == e || j1 == e) ? 1 : 0;
    ps[tid] = flag;
    __syncthreads();
    for (int off = 1; off < 256; off <<= 1) {
      int v = (tid >= off) ? ps[tid - off] : 0;
      __syncthreads();
      ps[tid] += v;
      __syncthreads();
    }
    int pos = sbase + ps[tid] - flag;  // exclusive prefix
    if (flag) {
      int s = (pos < ECAP) ? pos : -1;
      if (s >= 0) perm[e * ECAP + s] = token;
      if (j0 == e) slot[token * 2] = s;
      else slot[token * 2 + 1] = s;
    }
    __syncthreads();
    if (tid == 0) sbase += ps[255];
    __syncthreads();
  }
  if (tid == 0) count[e] = (sbase < ECAP) ? sbase : ECAP;
}

// ---------------- token-side gather of expert outputs, add into x ----------------
__global__ __launch_bounds__(256) void k_moe_add(
    const float* __restrict__ ybuf,
    const int* __restrict__ topi, const int* __restrict__ slot,
    const float* __restrict__ gate, float* __restrict__ x) {
  int token = blockIdx.x, tid = threadIdx.x;
  int e0 = topi[token * 2], s0 = slot[token * 2];
  int e1 = topi[token * 2 + 1], s1 = slot[token * 2 + 1];
  float g0 = gate[token * 2], g1 = gate[token * 2 + 1];
  const float* y0 = ybuf + ((size_t)e0 * ECAP + (s0 < 0 ? 0 : s0)) * CDIM;
  const float* y1 = ybuf + ((size_t)e1 * ECAP + (s1 < 0 ? 0 : s1)) * CDIM;
  float* xr = x + (size_t)token * CDIM;
  for (int c = tid; c < CDIM; c += 256) {
    float v = xr[c];
    if (s0 >= 0) v += g0 * y0[c];
    if (s1 >= 0) v += g1 * y1[c];
    xr[c] = v;
  }
}

// ---------------- head: out = xn @ head_w + head_b ----------------
__global__ __launch_bounds__(256) void k_head(const float* __restrict__ xn,
    const float* __restrict__ hw, const float* __restrict__ hb,
    float* __restrict__ out) {
  __shared__ float red[256];
  int token = blockIdx.x, tid = threadIdx.x;
  const float* xr = xn + (size_t)token * CDIM;
  float s = 0.f;
  for (int c = tid; c < CDIM; c += 256) s += xr[c] * hw[c];
  red[tid] = s; __syncthreads();
  for (int off = 128; off > 0; off >>= 1) {
    if (tid < off) red[tid] += red[tid + off];
    __syncthreads();
  }
  if (tid == 0) out[token] = red[0] + hb[0];
}

extern "C" void kernel_launch(void* const* d_in, const int* in_sizes, int n_in,
                              void* d_out, int out_size, void* d_ws, size_t ws_size,
                              hipStream_t stream) {
  const int* ids = (const int*)d_in[0];
  const float* tok_emb = (const float*)d_in[1];
  const float* pos_emb = (const float*)d_in[2];
  const float* ln1_g = (const float*)d_in[3];
  const float* ln1_b = (const float*)d_in[4];
  const float* ln2_g = (const float*)d_in[5];
  const float* ln2_b = (const float*)d_in[6];
  const float* qkv_w = (const float*)d_in[7];
  const float* out_w = (const float*)d_in[8];
  const float* route_w = (const float*)d_in[9];
  const float* route_b = (const float*)d_in[10];
  const float* noise_w = (const float*)d_in[11];
  const float* noise_b = (const float*)d_in[12];
  const float* w1 = (const float*)d_in[13];
  const float* b1 = (const float*)d_in[14];
  const float* w2 = (const float*)d_in[15];
  const float* b2 = (const float*)d_in[16];
  const float* lnf_g = (const float*)d_in[17];
  const float* lnf_b = (const float*)d_in[18];
  const float* head_w = (const float*)d_in[19];
  const float* head_b = (const float*)d_in[20];
  float* out = (float*)d_out;

  const size_t MB = 1024u * 1024u;
  char* ws = (char*)d_ws;
  // Big path: batch all 8 experts' h-activations (128 MB) so one launch
  // covers the whole MoE FFN. Needs 192 MB + small region.
  const bool big = ws_size >= (size_t)194 * MB;

  float* x    = (float*)(ws);              // 16MB: residual stream
  float* xn   = (float*)(ws + 16 * MB);    // 16MB: LN out / attn out (o)
  float* qkv  = (float*)(ws + 32 * MB);    // 48MB (dead after k_attn)
  float* hbuf = (float*)(ws + 32 * MB);    // aliases qkv; 16MB (small) / 128MB (big)
  float* ybuf = big ? (float*)(ws + 160 * MB)   // 32MB
                    : (float*)(ws + 48 * MB);   // 32MB
  char* small = big ? (ws + 192 * MB) : (ws + 80 * MB);
  int* topi = (int*)small;                 // 2*NTOK ints
  int* slot = topi + 2 * NTOK;             // 2*NTOK ints
  float* gate = (float*)(slot + 2 * NTOK); // 2*NTOK floats
  int* perm = (int*)(gate + 2 * NTOK);     // NEXP*ECAP ints
  int* count = perm + NEXP * ECAP;         // NEXP ints

  k_embed<<<NTOK, 256, 0, stream>>>(ids, tok_emb, pos_emb, x);

  for (int l = 0; l < 2; l++) {
    k_ln<<<NTOK, 256, 0, stream>>>(x, xn, ln1_g + l * CDIM, ln1_b + l * CDIM);
    // qkv = xn @ qkv_w[l]   (4096 x 3072 x 1024)
    k_gemm<<<dim3(3 * CDIM / 128, NTOK / 128, 1), 256, 0, stream>>>(xn, CDIM,
        qkv_w + (size_t)l * CDIM * 3 * CDIM, 3 * CDIM, qkv, 3 * CDIM,
        NTOK, 3 * CDIM, CDIM, nullptr, nullptr, nullptr, 0,
        0, 0, 0, 0, 0);
    // attention -> o (into xn region)
    k_attn<<<dim3(TSEQ / 128, NHEAD, 2), 256, 0, stream>>>(qkv, xn);
    // x += o @ out_w[l]
    k_gemm<<<dim3(CDIM / 128, NTOK / 128, 1), 256, 0, stream>>>(xn, CDIM,
        out_w + (size_t)l * CDIM * CDIM, CDIM, x, CDIM,
        NTOK, CDIM, CDIM, nullptr, nullptr, nullptr, 2,
        0, 0, 0, 0, 0);
    // ln2 -> xn
    k_ln<<<NTOK, 256, 0, stream>>>(x, xn, ln2_g + l * CDIM, ln2_b + l * CDIM);
    // router
    k_route<<<NTOK, 256, 0, stream>>>(xn,
        route_w + (size_t)l * CDIM * NEXP, route_b + l * NEXP,
        noise_w + (size_t)l * CDIM * NEXP, noise_b + l * NEXP,
        l, topi, gate);
    k_scan<<<NEXP, 256, 0, stream>>>(topi, perm, slot, count);
    // expert FFNs
    if (big) {
      // h = relu(xn[perm_e] @ w1_e + b1_e) for all 8 experts in one launch
      k_gemm<<<dim3(HIDN / 128, ECAP / 128, NEXP), 256, 0, stream>>>(xn, CDIM,
          w1 + (size_t)l * NEXP * CDIM * HIDN, HIDN, hbuf, HIDN,
          ECAP, HIDN, CDIM, b1 + (size_t)l * NEXP * HIDN, perm, count, 1,
          0, (size_t)CDIM * HIDN, (size_t)ECAP * HIDN, HIDN, ECAP);
      // y = h_e @ w2_e + b2_e for all 8 experts in one launch
      k_gemm<<<dim3(CDIM / 128, ECAP / 128, NEXP), 256, 0, stream>>>(hbuf, HIDN,
          w2 + (size_t)l * NEXP * HIDN * CDIM, CDIM, ybuf, CDIM,
          ECAP, CDIM, HIDN, b2 + (size_t)l * NEXP * CDIM, nullptr, count, 0,
          (size_t)ECAP * HIDN, (size_t)HIDN * CDIM, (size_t)ECAP * CDIM, CDIM, 0);
    } else {
      for (int e = 0; e < NEXP; e++) {
        const size_t we = (size_t)(l * NEXP + e);
        k_gemm<<<dim3(HIDN / 128, ECAP / 128, 1), 256, 0, stream>>>(xn, CDIM,
            w1 + we * CDIM * HIDN, HIDN, hbuf, HIDN,
            ECAP, HIDN, CDIM, b1 + we * HIDN, perm + e * ECAP, count + e, 1,
            0, 0, 0, 0, 0);
        k_gemm<<<dim3(CDIM / 128, ECAP / 128, 1), 256, 0, stream>>>(hbuf, HIDN,
            w2 + we * HIDN * CDIM, CDIM, ybuf + (size_t)e * ECAP * CDIM, CDIM,
            ECAP, CDIM, HIDN, b2 + we * CDIM, nullptr, count + e, 0,
            0, 0, 0, 0, 0);
      }
    }
    k_moe_add<<<NTOK, 256, 0, stream>>>(ybuf, topi, slot, gate, x);
  }

  k_ln<<<NTOK, 256, 0, stream>>>(x, xn, lnf_g, lnf_b);
  k_head<<<NTOK, 256, 0, stream>>>(xn, head_w, head_b, out);
}

// Round 3
// 4853.151 us; speedup vs baseline: 2.9070x; 1.2066x over previous
//
#include <hip/hip_runtime.h>
#include <stdint.h>
#include <math.h>

// Problem constants
#define NTOK 4096   // B*T
#define TSEQ 2048
#define CDIM 1024
#define NHEAD 16
#define DHEAD 64
#define NEXP 8
#define HIDN 4096
#define ECAP 1024

typedef short bf16x8 __attribute__((ext_vector_type(8)));
typedef float f32x4 __attribute__((ext_vector_type(4)));

// ---------------- threefry2x32 (exact JAX semantics) ----------------
__device__ __forceinline__ void threefry2x32(uint32_t k0, uint32_t k1,
                                             uint32_t x0, uint32_t x1,
                                             uint32_t& o0, uint32_t& o1) {
  uint32_t ks2 = k0 ^ k1 ^ 0x1BD11BDAu;
#define TF_R(r) { x0 += x1; x1 = (x1 << (r)) | (x1 >> (32 - (r))); x1 ^= x0; }
  x0 += k0; x1 += k1;
  TF_R(13) TF_R(15) TF_R(26) TF_R(6)
  x0 += k1; x1 += ks2 + 1u;
  TF_R(17) TF_R(29) TF_R(16) TF_R(24)
  x0 += ks2; x1 += k0 + 2u;
  TF_R(13) TF_R(15) TF_R(26) TF_R(6)
  x0 += k0; x1 += k1 + 3u;
  TF_R(17) TF_R(29) TF_R(16) TF_R(24)
  x0 += k1; x1 += ks2 + 4u;
  TF_R(13) TF_R(15) TF_R(26) TF_R(6)
  x0 += ks2; x1 += k0 + 5u;
#undef TF_R
  o0 = x0; o1 = x1;
}

// XLA's f32 erf_inv (Giles 2012 polynomial, log1p variant)
__device__ __forceinline__ float erfinv_f32(float x) {
  float w = -log1pf(-x * x);
  float p;
  if (w < 5.0f) {
    w = w - 2.5f;
    p = 2.81022636e-08f;
    p = fmaf(p, w, 3.43273939e-07f);
    p = fmaf(p, w, -3.5233877e-06f);
    p = fmaf(p, w, -4.39150654e-06f);
    p = fmaf(p, w, 0.00021858087f);
    p = fmaf(p, w, -0.00125372503f);
    p = fmaf(p, w, -0.00417768164f);
    p = fmaf(p, w, 0.246640727f);
    p = fmaf(p, w, 1.50140941f);
  } else {
    w = sqrtf(w) - 3.0f;
    p = -0.000200214257f;
    p = fmaf(p, w, 0.000100950558f);
    p = fmaf(p, w, 0.00134934322f);
    p = fmaf(p, w, -0.00367342844f);
    p = fmaf(p, w, 0.00573950773f);
    p = fmaf(p, w, -0.0076224613f);
    p = fmaf(p, w, 0.00943887047f);
    p = fmaf(p, w, 1.00167406f);
    p = fmaf(p, w, 2.83297682f);
  }
  return p * x;
}

// split fp32 pair -> packed bf16 hi-plane word and lo-plane word
// hi = (bf16(x1)<<16)|bf16(x0); lo captures the residual x - float(hi)
__device__ __forceinline__ void split2(float x0, float x1,
                                       uint32_t& hi, uint32_t& lo) {
  uint32_t h, l;
  asm("v_cvt_pk_bf16_f32 %0, %1, %2" : "=v"(h) : "v"(x0), "v"(x1));
  float h0 = __uint_as_float(h << 16);
  float h1 = __uint_as_float(h & 0xffff0000u);
  asm("v_cvt_pk_bf16_f32 %0, %1, %2" : "=v"(l) : "v"(x0 - h0), "v"(x1 - h1));
  hi = h; lo = l;
}

// ---------------- embedding ----------------
__global__ __launch_bounds__(256) void k_embed(const int* __restrict__ ids,
    const float* __restrict__ tok, const float* __restrict__ pos,
    float* __restrict__ x) {
  int row = blockIdx.x;
  int id = ids[row];
  int t = row & (TSEQ - 1);
  const float* tr = tok + (size_t)id * CDIM;
  const float* pr = pos + (size_t)t * CDIM;
  float* xr = x + (size_t)row * CDIM;
  for (int c = threadIdx.x; c < CDIM; c += 256) xr[c] = tr[c] + pr[c];
}

// ---------------- layernorm (two-pass, matches jnp.var) ----------------
__global__ __launch_bounds__(256) void k_ln(const float* __restrict__ in,
    float* __restrict__ out, const float* __restrict__ g, const float* __restrict__ b) {
  __shared__ float red[256];
  int row = blockIdx.x, tid = threadIdx.x;
  const float* xr = in + (size_t)row * CDIM;
  float s = 0.f;
  for (int c = tid; c < CDIM; c += 256) s += xr[c];
  red[tid] = s; __syncthreads();
  for (int off = 128; off > 0; off >>= 1) {
    if (tid < off) red[tid] += red[tid + off];
    __syncthreads();
  }
  float m = red[0] * (1.0f / CDIM);
  __syncthreads();
  float v = 0.f;
  for (int c = tid; c < CDIM; c += 256) { float d = xr[c] - m; v += d * d; }
  red[tid] = v; __syncthreads();
  for (int off = 128; off > 0; off >>= 1) {
    if (tid < off) red[tid] += red[tid + off];
    __syncthreads();
  }
  float var = red[0] * (1.0f / CDIM);
  float rstd = 1.0f / sqrtf(var + 1e-5f);
  float* orow = out + (size_t)row * CDIM;
  for (int c = tid; c < CDIM; c += 256)
    orow[c] = (xr[c] - m) * rstd * g[c] + b[c];
}

// ---------------- MFMA GEMM, bf16x3 split (fp32-equivalent accuracy) ----------------
// 128x128 tile per 256-thread block (4 waves x 64x64), K-step 32.
// A,B read fp32 from global, split on the fly into bf16 hi/lo planes in LDS;
// product = Ah*Bh + Ah*Bl + Al*Bh accumulated in fp32 via mfma_f32_16x16x32_bf16.
// Interfaces identical to the previous fp32 GEMM (drop-in at all call sites).
__global__ __launch_bounds__(256, 2) void k_gemm(
    const float* __restrict__ A, int lda,
    const float* __restrict__ B, int ldb,
    float* __restrict__ Cm, int ldc,
    int M, int N, int K,
    const float* __restrict__ bias,
    const int* __restrict__ gather,
    const int* __restrict__ countPtr,
    int flags,
    size_t zsA, size_t zsB, size_t zsC, int zsBias, int zsGather) {
  __shared__ short Ah[128][40];  // [row][k], stride 40 (pad 8): 2-way-only banks
  __shared__ short Al[128][40];
  __shared__ short Bh[128][40];  // [col][k] (transposed at stage)
  __shared__ short Bl[128][40];
  const int z = blockIdx.z;
  A += (size_t)z * zsA;
  B += (size_t)z * zsB;
  Cm += (size_t)z * zsC;
  if (bias) bias += (size_t)z * (size_t)zsBias;
  if (gather) gather += (size_t)z * (size_t)zsGather;
  int Meff = M;
  if (countPtr) { int cc = countPtr[z]; if (cc < Meff) Meff = cc; }
  const int row0 = blockIdx.y << 7, col0 = blockIdx.x << 7;
  if (row0 >= Meff) return;
  const int tid = threadIdx.x;

  // staging maps: A: thread -> (row ar, 16 k starting at ak)
  const int ar = tid >> 1, ak = (tid & 1) << 4;
  // B: thread -> (4 k-rows starting at bk, 4 cols starting at bc)
  const int bk = (tid >> 5) << 2, bc = (tid & 31) << 2;

  const int agrow = row0 + ar;
  const float* aP = nullptr;
  if (agrow < Meff) aP = A + (size_t)(gather ? gather[agrow] : agrow) * lda + ak;
  const float* bP = B + (size_t)bk * ldb + col0 + bc;

  const float4 z4 = make_float4(0.f, 0.f, 0.f, 0.f);
  float4 aR[4], bR[4];
#pragma unroll
  for (int j = 0; j < 4; ++j) {
    aR[j] = aP ? *(const float4*)(aP + (j << 2)) : z4;
    bR[j] = *(const float4*)(bP + (size_t)j * ldb);
  }

  // compute-side indices
  const int lane = tid & 63, wv = tid >> 6;
  const int wr = (wv >> 1) << 6, wc = (wv & 1) << 6;   // wave origin in tile
  const int lr = lane & 15;
  const int k8 = (lane >> 4) << 3;       // fragment k-offset (8 contiguous)
  const int qrow = (lane >> 4) << 2;     // C/D row group

  f32x4 acc[4][4];
#pragma unroll
  for (int i = 0; i < 4; ++i)
#pragma unroll
    for (int j = 0; j < 4; ++j) acc[i][j] = (f32x4)0.f;

  for (int k0 = 0; k0 < K; k0 += 32) {
    // ---- convert staged regs -> bf16 hi/lo planes in LDS
    {
      uint32_t h[8], l[8];
      split2(aR[0].x, aR[0].y, h[0], l[0]);
      split2(aR[0].z, aR[0].w, h[1], l[1]);
      split2(aR[1].x, aR[1].y, h[2], l[2]);
      split2(aR[1].z, aR[1].w, h[3], l[3]);
      split2(aR[2].x, aR[2].y, h[4], l[4]);
      split2(aR[2].z, aR[2].w, h[5], l[5]);
      split2(aR[3].x, aR[3].y, h[6], l[6]);
      split2(aR[3].z, aR[3].w, h[7], l[7]);
      *(uint4*)&Ah[ar][ak]     = make_uint4(h[0], h[1], h[2], h[3]);
      *(uint4*)&Ah[ar][ak + 8] = make_uint4(h[4], h[5], h[6], h[7]);
      *(uint4*)&Al[ar][ak]     = make_uint4(l[0], l[1], l[2], l[3]);
      *(uint4*)&Al[ar][ak + 8] = make_uint4(l[4], l[5], l[6], l[7]);
    }
    {
      uint32_t h01, l01, h23, l23;
      split2(bR[0].x, bR[1].x, h01, l01); split2(bR[2].x, bR[3].x, h23, l23);
      *(uint2*)&Bh[bc + 0][bk] = make_uint2(h01, h23);
      *(uint2*)&Bl[bc + 0][bk] = make_uint2(l01, l23);
      split2(bR[0].y, bR[1].y, h01, l01); split2(bR[2].y, bR[3].y, h23, l23);
      *(uint2*)&Bh[bc + 1][bk] = make_uint2(h01, h23);
      *(uint2*)&Bl[bc + 1][bk] = make_uint2(l01, l23);
      split2(bR[0].z, bR[1].z, h01, l01); split2(bR[2].z, bR[3].z, h23, l23);
      *(uint2*)&Bh[bc + 2][bk] = make_uint2(h01, h23);
      *(uint2*)&Bl[bc + 2][bk] = make_uint2(l01, l23);
      split2(bR[0].w, bR[1].w, h01, l01); split2(bR[2].w, bR[3].w, h23, l23);
      *(uint2*)&Bh[bc + 3][bk] = make_uint2(h01, h23);
      *(uint2*)&Bl[bc + 3][bk] = make_uint2(l01, l23);
    }
    __syncthreads();
    // ---- prefetch next K-tile (in flight during MFMA block)
    const int kn = k0 + 32;
    if (kn < K) {
#pragma unroll
      for (int j = 0; j < 4; ++j) {
        aR[j] = aP ? *(const float4*)(aP + kn + (j << 2)) : z4;
        bR[j] = *(const float4*)(bP + (size_t)(kn + j) * ldb);
      }
    }
    // ---- MFMA: 4x4 fragment tiles, 3 products each
    bf16x8 vbh[4], vbl[4];
#pragma unroll
    for (int nt = 0; nt < 4; ++nt) {
      vbh[nt] = *(const bf16x8*)&Bh[wc + nt * 16 + lr][k8];
      vbl[nt] = *(const bf16x8*)&Bl[wc + nt * 16 + lr][k8];
    }
#pragma unroll
    for (int mt = 0; mt < 4; ++mt) {
      const bf16x8 vah = *(const bf16x8*)&Ah[wr + mt * 16 + lr][k8];
      const bf16x8 val = *(const bf16x8*)&Al[wr + mt * 16 + lr][k8];
#pragma unroll
      for (int nt = 0; nt < 4; ++nt) {
        acc[mt][nt] = __builtin_amdgcn_mfma_f32_16x16x32_bf16(vah, vbh[nt], acc[mt][nt], 0, 0, 0);
        acc[mt][nt] = __builtin_amdgcn_mfma_f32_16x16x32_bf16(vah, vbl[nt], acc[mt][nt], 0, 0, 0);
        acc[mt][nt] = __builtin_amdgcn_mfma_f32_16x16x32_bf16(val, vbh[nt], acc[mt][nt], 0, 0, 0);
      }
    }
    __syncthreads();
  }

  // ---- epilogue: D lane layout col=lane&15, row=(lane>>4)*4+q
#pragma unroll
  for (int mt = 0; mt < 4; ++mt) {
#pragma unroll
    for (int nt = 0; nt < 4; ++nt) {
      const int gc = col0 + wc + nt * 16 + lr;
      const int gr0 = row0 + wr + mt * 16 + qrow;
#pragma unroll
      for (int q = 0; q < 4; ++q) {
        const int gr = gr0 + q;
        if (gr >= Meff) continue;
        float v = acc[mt][nt][q];
        if (bias) v += bias[gc];
        if (flags & 1) v = fmaxf(v, 0.f);
        float* cp = Cm + (size_t)gr * ldc + gc;
        if (flags & 2) v += *cp;
        *cp = v;
      }
    }
  }
}

// ---------------- attention: flash-style, register-blocked GEMM phases ----------------
// Block: 128 Q-rows x (head, batch). s-tiles of 64 keys. 256 threads.
// Phase A: S = Q@K^T (8x4/thread), phase B: in-register online softmax,
// phase C: O += P@V (8x4/thread). K transposed at stage (stride 66),
// Q/P d-major (stride 132), V natural (stride 68). ~99.5 KB LDS -> 1 block/CU.
__global__ __launch_bounds__(256, 1) void k_attn(const float* __restrict__ qkv,
                                                 float* __restrict__ o) {
  __shared__ float Qs[64][132];  // Qs[d][r], scaled by 1/8
  __shared__ float Ks[64][66];   // Ks[d][j]  (stride 66: b64 reads, 4-way stage writes)
  __shared__ float Vs[64][68];   // Vs[j][d]
  __shared__ float Ps[64][132];  // Ps[j][r]
  const int t0 = blockIdx.x << 7;
  const int h = blockIdx.y;
  const int b = blockIdx.z;
  const int tid = threadIdx.x;
  const int tx = tid & 15, ty = tid >> 4;
  const int r0 = ty << 2;   // rows r0..r0+3 and r0+64..r0+67
  const int c0 = tx << 2;   // cols c0..c0+3

  // ---- load Q tile (128 x 64), scale, store transposed (d-major)
#pragma unroll
  for (int p = 0; p < 8; ++p) {
    int idx = tid + (p << 8);
    int r = idx >> 4, d4 = (idx & 15) << 2;
    const float4 q = *(const float4*)(qkv +
        ((size_t)(b * TSEQ + t0 + r) * 3 + 0) * CDIM + h * DHEAD + d4);
    Qs[d4 + 0][r] = q.x * 0.125f;
    Qs[d4 + 1][r] = q.y * 0.125f;
    Qs[d4 + 2][r] = q.z * 0.125f;
    Qs[d4 + 3][r] = q.w * 0.125f;
  }

  float m0[8], l0[8], Oacc[8][4];
#pragma unroll
  for (int i = 0; i < 8; ++i) {
    m0[i] = -INFINITY; l0[i] = 0.f;
#pragma unroll
    for (int j = 0; j < 4; ++j) Oacc[i][j] = 0.f;
  }

  // prologue: prefetch K/V tile 0 into registers
  float4 kreg[4], vreg[4];
#pragma unroll
  for (int p = 0; p < 4; ++p) {
    int idx = tid + (p << 8);
    int j = idx >> 4, d4 = (idx & 15) << 2;
    kreg[p] = *(const float4*)(qkv + ((size_t)(b * TSEQ + j) * 3 + 1) * CDIM + h * DHEAD + d4);
    vreg[p] = *(const float4*)(qkv + ((size_t)(b * TSEQ + j) * 3 + 2) * CDIM + h * DHEAD + d4);
  }

  for (int s0 = 0; s0 < TSEQ; s0 += 64) {
    // write staged K (transposed) and V tiles to LDS
#pragma unroll
    for (int p = 0; p < 4; ++p) {
      int idx = tid + (p << 8);
      int j = idx >> 4, d4 = (idx & 15) << 2;
      Ks[d4 + 0][j] = kreg[p].x;
      Ks[d4 + 1][j] = kreg[p].y;
      Ks[d4 + 2][j] = kreg[p].z;
      Ks[d4 + 3][j] = kreg[p].w;
      *(float4*)&Vs[j][d4] = vreg[p];
    }
    __syncthreads();
    // prefetch next s-tile (hidden under phases A-C)
    if (s0 + 64 < TSEQ) {
#pragma unroll
      for (int p = 0; p < 4; ++p) {
        int idx = tid + (p << 8);
        int j = idx >> 4, d4 = (idx & 15) << 2;
        kreg[p] = *(const float4*)(qkv + ((size_t)(b * TSEQ + s0 + 64 + j) * 3 + 1) * CDIM + h * DHEAD + d4);
        vreg[p] = *(const float4*)(qkv + ((size_t)(b * TSEQ + s0 + 64 + j) * 3 + 2) * CDIM + h * DHEAD + d4);
      }
    }
    // ---- phase A: S = Q @ K^T (8x4 per thread)
    float sacc[8][4];
#pragma unroll
    for (int i = 0; i < 8; ++i)
#pragma unroll
      for (int j = 0; j < 4; ++j) sacc[i][j] = 0.f;
#pragma unroll 8
    for (int kk = 0; kk < 64; ++kk) {
      const float4 qa = *(const float4*)&Qs[kk][r0];
      const float4 qb = *(const float4*)&Qs[kk][r0 + 64];
      const float2 ka = *(const float2*)&Ks[kk][c0];
      const float2 kb = *(const float2*)&Ks[kk][c0 + 2];
      const float av[8] = {qa.x, qa.y, qa.z, qa.w, qb.x, qb.y, qb.z, qb.w};
      const float bv[4] = {ka.x, ka.y, kb.x, kb.y};
#pragma unroll
      for (int i = 0; i < 8; ++i)
#pragma unroll
        for (int j = 0; j < 4; ++j) sacc[i][j] = fmaf(av[i], bv[j], sacc[i][j]);
    }
    // ---- phase B: online softmax (row = 16 contiguous lanes), write P
    float pv[8][4];
#pragma unroll
    for (int i = 0; i < 8; ++i) {
      float mx = fmaxf(fmaxf(sacc[i][0], sacc[i][1]), fmaxf(sacc[i][2], sacc[i][3]));
#pragma unroll
      for (int off = 8; off > 0; off >>= 1) mx = fmaxf(mx, __shfl_xor(mx, off, 16));
      float mnew = fmaxf(m0[i], mx);
      float alpha = expf(m0[i] - mnew);
      float psum = 0.f;
#pragma unroll
      for (int j = 0; j < 4; ++j) {
        float p = expf(sacc[i][j] - mnew);
        pv[i][j] = p;
        psum += p;
      }
#pragma unroll
      for (int off = 8; off > 0; off >>= 1) psum += __shfl_xor(psum, off, 16);
      l0[i] = l0[i] * alpha + psum;
      m0[i] = mnew;
#pragma unroll
      for (int j = 0; j < 4; ++j) Oacc[i][j] *= alpha;
    }
#pragma unroll
    for (int jj = 0; jj < 4; ++jj) {
      *(float4*)&Ps[c0 + jj][r0] =
          make_float4(pv[0][jj], pv[1][jj], pv[2][jj], pv[3][jj]);
      *(float4*)&Ps[c0 + jj][r0 + 64] =
          make_float4(pv[4][jj], pv[5][jj], pv[6][jj], pv[7][jj]);
    }
    __syncthreads();
    // ---- phase C: O += P @ V (8x4 per thread)
#pragma unroll 8
    for (int kk = 0; kk < 64; ++kk) {
      const float4 pa = *(const float4*)&Ps[kk][r0];
      const float4 pb = *(const float4*)&Ps[kk][r0 + 64];
      const float4 vv = *(const float4*)&Vs[kk][c0];
      const float av[8] = {pa.x, pa.y, pa.z, pa.w, pb.x, pb.y, pb.z, pb.w};
      const float bv[4] = {vv.x, vv.y, vv.z, vv.w};
#pragma unroll
      for (int i = 0; i < 8; ++i)
#pragma unroll
        for (int j = 0; j < 4; ++j) Oacc[i][j] = fmaf(av[i], bv[j], Oacc[i][j]);
    }
    __syncthreads();
  }
  // ---- epilogue: normalize and store
#pragma unroll
  for (int i = 0; i < 8; ++i) {
    int r = t0 + ((i < 4) ? (r0 + i) : (r0 + 60 + i));  // second half: +64
    float inv = 1.0f / l0[i];
    float4 v;
    v.x = Oacc[i][0] * inv; v.y = Oacc[i][1] * inv;
    v.z = Oacc[i][2] * inv; v.w = Oacc[i][3] * inv;
    *(float4*)(o + (size_t)(b * TSEQ + r) * CDIM + h * DHEAD + c0) = v;
  }
}

// ---------------- router: logits + threefry noise + top-2 ----------------
__global__ __launch_bounds__(256) void k_route(
    const float* __restrict__ xn,
    const float* __restrict__ rw, const float* __restrict__ rb,
    const float* __restrict__ nw, const float* __restrict__ nb,
    int layer, int* __restrict__ topi, float* __restrict__ gate) {
  int token = blockIdx.x, tid = threadIdx.x;
  float acc[16];
#pragma unroll
  for (int j = 0; j < 16; j++) acc[j] = 0.f;
  const float* xr = xn + (size_t)token * CDIM;
  for (int c = tid; c < CDIM; c += 256) {
    float xc = xr[c];
    const float* w1p = rw + (size_t)c * NEXP;
    const float* w2p = nw + (size_t)c * NEXP;
#pragma unroll
    for (int j = 0; j < 8; j++) acc[j] += xc * w1p[j];
#pragma unroll
    for (int j = 0; j < 8; j++) acc[8 + j] += xc * w2p[j];
  }
#pragma unroll
  for (int j = 0; j < 16; j++) {
#pragma unroll
    for (int off = 32; off > 0; off >>= 1) acc[j] += __shfl_xor(acc[j], off, 64);
  }
  __shared__ float wp[4][16];
  int wid = tid >> 6;
  if ((tid & 63) == 0) {
#pragma unroll
    for (int j = 0; j < 16; j++) wp[wid][j] = acc[j];
  }
  __syncthreads();
  __shared__ float noisy[8];
  if (tid < 8) {
    int j = tid;
    float logit = wp[0][j] + wp[1][j] + wp[2][j] + wp[3][j] + rb[j];
    float nl = wp[0][8 + j] + wp[1][8 + j] + wp[2][8 + j] + wp[3][8 + j] + nb[j];
    float sp = fmaxf(nl, 0.f) + log1pf(expf(-fabsf(nl)));  // softplus
    // key_l = fold_in(key(42), layer) = threefry((0,42),(0,layer))
    uint32_t k0, k1, o0, o1;
    threefry2x32(0u, 42u, 0u, (uint32_t)layer, k0, k1);
    // partitionable random_bits: counter = (0, i), bits = o0 ^ o1
    uint32_t idx = (uint32_t)(token * NEXP + j);
    threefry2x32(k0, k1, 0u, idx, o0, o1);
    uint32_t bits = o0 ^ o1;
    float f = __uint_as_float((bits >> 9) | 0x3f800000u) - 1.0f;  // [0,1)
    const float lo = -0.99999994f;  // nextafter(-1,0); (hi-lo) rounds to 2.0f
    float u = fmaxf(lo, f * 2.0f + lo);
    float z = 1.41421356f * erfinv_f32(u);
    noisy[j] = logit + z * sp;
  }
  __syncthreads();
  if (tid == 0) {
    float v1 = -INFINITY; int i1 = 0;
#pragma unroll
    for (int j = 0; j < 8; j++) { float v = noisy[j]; if (v > v1) { v1 = v; i1 = j; } }
    float v2 = -INFINITY; int i2 = 0;
#pragma unroll
    for (int j = 0; j < 8; j++) {
      if (j == i1) continue;
      float v = noisy[j]; if (v > v2) { v2 = v; i2 = j; }
    }
    float e2 = expf(v2 - v1);
    float denom = 1.0f + e2;
    topi[token * 2] = i1; topi[token * 2 + 1] = i2;
    gate[token * 2] = 1.0f / denom;
    gate[token * 2 + 1] = e2 / denom;
  }
}

// ---------------- per-expert capacity scan (stable token order) ----------------
__global__ __launch_bounds__(256) void k_scan(const int* __restrict__ topi,
    int* __restrict__ perm, int* __restrict__ slot, int* __restrict__ count) {
  int e = blockIdx.x, tid = threadIdx.x;
  __shared__ int ps[256];
  __shared__ int sbase;
  if (tid == 0) sbase = 0;
  __syncthreads();
  for (int c0 = 0; c0 < NTOK; c0 += 256) {
    int token = c0 + tid;
    int j0 = topi[token * 2], j1 = topi[token * 2 + 1];
    int flag = (j0 == e || j1 == e) ? 1 : 0;
    ps[tid] = flag;
    __syncthreads();
    for (int off = 1; off < 256; off <<= 1) {
      int v = (tid >= off) ? ps[tid - off] : 0;
      __syncthreads();
      ps[tid] += v;
      __syncthreads();
    }
    int pos = sbase + ps[tid] - flag;  // exclusive prefix
    if (flag) {
      int s = (pos < ECAP) ? pos : -1;
      if (s >= 0) perm[e * ECAP + s] = token;
      if (j0 == e) slot[token * 2] = s;
      else slot[token * 2 + 1] = s;
    }
    __syncthreads();
    if (tid == 0) sbase += ps[255];
    __syncthreads();
  }
  if (tid == 0) count[e] = (sbase < ECAP) ? sbase : ECAP;
}

// ---------------- token-side gather of expert outputs, add into x ----------------
__global__ __launch_bounds__(256) void k_moe_add(
    const float* __restrict__ ybuf,
    const int* __restrict__ topi, const int* __restrict__ slot,
    const float* __restrict__ gate, float* __restrict__ x) {
  int token = blockIdx.x, tid = threadIdx.x;
  int e0 = topi[token * 2], s0 = slot[token * 2];
  int e1 = topi[token * 2 + 1], s1 = slot[token * 2 + 1];
  float g0 = gate[token * 2], g1 = gate[token * 2 + 1];
  const float* y0 = ybuf + ((size_t)e0 * ECAP + (s0 < 0 ? 0 : s0)) * CDIM;
  const float* y1 = ybuf + ((size_t)e1 * ECAP + (s1 < 0 ? 0 : s1)) * CDIM;
  float* xr = x + (size_t)token * CDIM;
  for (int c = tid; c < CDIM; c += 256) {
    float v = xr[c];
    if (s0 >= 0) v += g0 * y0[c];
    if (s1 >= 0) v += g1 * y1[c];
    xr[c] = v;
  }
}

// ---------------- head: out = xn @ head_w + head_b ----------------
__global__ __launch_bounds__(256) void k_head(const float* __restrict__ xn,
    const float* __restrict__ hw, const float* __restrict__ hb,
    float* __restrict__ out) {
  __shared__ float red[256];
  int token = blockIdx.x, tid = threadIdx.x;
  const float* xr = xn + (size_t)token * CDIM;
  float s = 0.f;
  for (int c = tid; c < CDIM; c += 256) s += xr[c] * hw[c];
  red[tid] = s; __syncthreads();
  for (int off = 128; off > 0; off >>= 1) {
    if (tid < off) red[tid] += red[tid + off];
    __syncthreads();
  }
  if (tid == 0) out[token] = red[0] + hb[0];
}

extern "C" void kernel_launch(void* const* d_in, const int* in_sizes, int n_in,
                              void* d_out, int out_size, void* d_ws, size_t ws_size,
                              hipStream_t stream) {
  const int* ids = (const int*)d_in[0];
  const float* tok_emb = (const float*)d_in[1];
  const float* pos_emb = (const float*)d_in[2];
  const float* ln1_g = (const float*)d_in[3];
  const float* ln1_b = (const float*)d_in[4];
  const float* ln2_g = (const float*)d_in[5];
  const float* ln2_b = (const float*)d_in[6];
  const float* qkv_w = (const float*)d_in[7];
  const float* out_w = (const float*)d_in[8];
  const float* route_w = (const float*)d_in[9];
  const float* route_b = (const float*)d_in[10];
  const float* noise_w = (const float*)d_in[11];
  const float* noise_b = (const float*)d_in[12];
  const float* w1 = (const float*)d_in[13];
  const float* b1 = (const float*)d_in[14];
  const float* w2 = (const float*)d_in[15];
  const float* b2 = (const float*)d_in[16];
  const float* lnf_g = (const float*)d_in[17];
  const float* lnf_b = (const float*)d_in[18];
  const float* head_w = (const float*)d_in[19];
  const float* head_b = (const float*)d_in[20];
  float* out = (float*)d_out;

  const size_t MB = 1024u * 1024u;
  char* ws = (char*)d_ws;
  // Big path: batch all 8 experts' h-activations (128 MB) so one launch
  // covers the whole MoE FFN. Needs 192 MB + small region.
  const bool big = ws_size >= (size_t)194 * MB;

  float* x    = (float*)(ws);              // 16MB: residual stream
  float* xn   = (float*)(ws + 16 * MB);    // 16MB: LN out / attn out (o)
  float* qkv  = (float*)(ws + 32 * MB);    // 48MB (dead after k_attn)
  float* hbuf = (float*)(ws + 32 * MB);    // aliases qkv; 16MB (small) / 128MB (big)
  float* ybuf = big ? (float*)(ws + 160 * MB)   // 32MB
                    : (float*)(ws + 48 * MB);   // 32MB
  char* small = big ? (ws + 192 * MB) : (ws + 80 * MB);
  int* topi = (int*)small;                 // 2*NTOK ints
  int* slot = topi + 2 * NTOK;             // 2*NTOK ints
  float* gate = (float*)(slot + 2 * NTOK); // 2*NTOK floats
  int* perm = (int*)(gate + 2 * NTOK);     // NEXP*ECAP ints
  int* count = perm + NEXP * ECAP;         // NEXP ints

  k_embed<<<NTOK, 256, 0, stream>>>(ids, tok_emb, pos_emb, x);

  for (int l = 0; l < 2; l++) {
    k_ln<<<NTOK, 256, 0, stream>>>(x, xn, ln1_g + l * CDIM, ln1_b + l * CDIM);
    // qkv = xn @ qkv_w[l]   (4096 x 3072 x 1024)
    k_gemm<<<dim3(3 * CDIM / 128, NTOK / 128, 1), 256, 0, stream>>>(xn, CDIM,
        qkv_w + (size_t)l * CDIM * 3 * CDIM, 3 * CDIM, qkv, 3 * CDIM,
        NTOK, 3 * CDIM, CDIM, nullptr, nullptr, nullptr, 0,
        0, 0, 0, 0, 0);
    // attention -> o (into xn region)
    k_attn<<<dim3(TSEQ / 128, NHEAD, 2), 256, 0, stream>>>(qkv, xn);
    // x += o @ out_w[l]
    k_gemm<<<dim3(CDIM / 128, NTOK / 128, 1), 256, 0, stream>>>(xn, CDIM,
        out_w + (size_t)l * CDIM * CDIM, CDIM, x, CDIM,
        NTOK, CDIM, CDIM, nullptr, nullptr, nullptr, 2,
        0, 0, 0, 0, 0);
    // ln2 -> xn
    k_ln<<<NTOK, 256, 0, stream>>>(x, xn, ln2_g + l * CDIM, ln2_b + l * CDIM);
    // router
    k_route<<<NTOK, 256, 0, stream>>>(xn,
        route_w + (size_t)l * CDIM * NEXP, route_b + l * NEXP,
        noise_w + (size_t)l * CDIM * NEXP, noise_b + l * NEXP,
        l, topi, gate);
    k_scan<<<NEXP, 256, 0, stream>>>(topi, perm, slot, count);
    // expert FFNs
    if (big) {
      // h = relu(xn[perm_e] @ w1_e + b1_e) for all 8 experts in one launch
      k_gemm<<<dim3(HIDN / 128, ECAP / 128, NEXP), 256, 0, stream>>>(xn, CDIM,
          w1 + (size_t)l * NEXP * CDIM * HIDN, HIDN, hbuf, HIDN,
          ECAP, HIDN, CDIM, b1 + (size_t)l * NEXP * HIDN, perm, count, 1,
          0, (size_t)CDIM * HIDN, (size_t)ECAP * HIDN, HIDN, ECAP);
      // y = h_e @ w2_e + b2_e for all 8 experts in one launch
      k_gemm<<<dim3(CDIM / 128, ECAP / 128, NEXP), 256, 0, stream>>>(hbuf, HIDN,
          w2 + (size_t)l * NEXP * HIDN * CDIM, CDIM, ybuf, CDIM,
          ECAP, CDIM, HIDN, b2 + (size_t)l * NEXP * CDIM, nullptr, count, 0,
          (size_t)ECAP * HIDN, (size_t)HIDN * CDIM, (size_t)ECAP * CDIM, CDIM, 0);
    } else {
      for (int e = 0; e < NEXP; e++) {
        const size_t we = (size_t)(l * NEXP + e);
        k_gemm<<<dim3(HIDN / 128, ECAP / 128, 1), 256, 0, stream>>>(xn, CDIM,
            w1 + we * CDIM * HIDN, HIDN, hbuf, HIDN,
            ECAP, HIDN, CDIM, b1 + we * HIDN, perm + e * ECAP, count + e, 1,
            0, 0, 0, 0, 0);
        k_gemm<<<dim3(CDIM / 128, ECAP / 128, 1), 256, 0, stream>>>(hbuf, HIDN,
            w2 + we * HIDN * CDIM, CDIM, ybuf + (size_t)e * ECAP * CDIM, CDIM,
            ECAP, CDIM, HIDN, b2 + we * CDIM, nullptr, count + e, 0,
            0, 0, 0, 0, 0);
      }
    }
    k_moe_add<<<NTOK, 256, 0, stream>>>(ybuf, topi, slot, gate, x);
  }

  k_ln<<<NTOK, 256, 0, stream>>>(x, xn, lnf_g, lnf_b);
  k_head<<<NTOK, 256, 0, stream>>>(xn, head_w, head_b, out);
}